// Round 15
// baseline (328.644 us; speedup 1.0000x reference)
//
#include <hip/hip_runtime.h>
#include <math.h>

#define TOK_PER_BLK 2
#define THREADS 256
#define NROWS 24
#define PCOL 68        // 64 partials + 4 pad
#define TAU_INV 20.0f  // 1/0.05
#define WCOPY 8        // weight replicas (per-XCD L2 affinity via blockIdx&7)
#define WROW_U32 2048  // uint32 per row
#define WCOPY_U32 (NROWS * WROW_U32)

typedef _Float16 half2_t __attribute__((ext_vector_type(2)));
typedef float    f32x4  __attribute__((ext_vector_type(4)));

// ---------------------------------------------------------------------------
// Prelude: fold (1+gamma) into the 24 weight rows, f16 pairs, PERMUTED so in
// hc_fused thread tid's two uint4 loads deliver the 16 k-elements matching
// its x quads (k = q*1024 + 4*tid .. +3, q=0..3). 8 identical copies;
// consecutive blocks (round-robin across XCDs) pick copy blockIdx&7.
// ---------------------------------------------------------------------------
__global__ void fold_gamma(const float* __restrict__ w_res,
                           const float* __restrict__ w_pre,
                           const float* __restrict__ w_post,
                           const float* __restrict__ gamma,
                           unsigned int* __restrict__ wf) {
    const int idx = blockIdx.x * THREADS + threadIdx.x;   // 0 .. 24*2048-1
    const int row = idx >> 11;
    const int j   = idx & 2047;
    const int o   = j >> 2;
    const int pp  = j & 3;
    const int t   = o & 255;
    const int quad = pp >> 1;
    int base;
    if (o < 256) base = (quad == 0) ? (4 * t)        : (1024 + 4 * t);
    else         base = (quad == 0) ? (2048 + 4 * t) : (3072 + 4 * t);
    const int k0 = base + 2 * (pp & 1);

    const float* src = (row < 16) ? (w_res + ((size_t)row << 12))
                     : (row < 20) ? (w_pre + ((size_t)(row - 16) << 12))
                                  : (w_post + ((size_t)(row - 20) << 12));
    float v0 = src[k0]     * (1.0f + gamma[k0]);
    float v1 = src[k0 + 1] * (1.0f + gamma[k0 + 1]);
    union { _Float16 h[2]; unsigned int u; } cvt;
    cvt.h[0] = (_Float16)v0;
    cvt.h[1] = (_Float16)v1;
    #pragma unroll
    for (int c = 0; c < WCOPY; ++c)
        wf[(size_t)c * WCOPY_U32 + idx] = cvt.u;
}

// ---------------------------------------------------------------------------
// R19 = R17 + barrier-#2 elimination RETRIED with R18's confounds removed:
//   - R18's 524288 bank conflicts: merged reduce read row 2idx+m at stride-68
//     rows -> start bank 4(2idx+m): lanes {idx,idx+4,idx+8,idx+12} 4-way
//     collided. FIX: lane idx starts its 16-float4 sweep at column idx and
//     wraps ((idx+j)&15): wrap is bank-neutral (64 floats = 0 mod 32) and
//     start banks 4(3idx+m) -> worst 2-way (free, per LDS µbench).
//   - R18's VGPR 92 / occ 22%: pre-phase-1 weight preload held 64 regs live
//     across the x burst. FIX: preload back to R17 placement (after phase 1).
// Keeps: TOK=2, nt x/out streams, 8x replicas (blockIdx&7), depth-4 weight
// prefetch, DPP quad-reduce, split fdot2 accumulators.
// ALLOCATOR LAW (R4/5/7/8/13): keep (256,2); load bursts <= 8 per window.
// Tripwire: WRITE_SIZE != 131072 KB = spill; BANK_CONFLICT >> 4096 = stagger
// wrong. Pre-committed: dur >= 88 -> convoy theory dead, revert R15 + stop.
// ---------------------------------------------------------------------------
__global__ __launch_bounds__(THREADS, 2)
void hc_fused(const float* __restrict__ resid,
              const unsigned int* __restrict__ wf,
              const float* __restrict__ beta_res,
              const float* __restrict__ beta_pre,
              const float* __restrict__ beta_post,
              const float* __restrict__ p_alpha_res,
              const float* __restrict__ p_alpha_pre,
              const float* __restrict__ p_alpha_post,
              float* __restrict__ out)
{
    __shared__ __align__(16) float sh_part[NROWS * TOK_PER_BLK][PCOL]; // 13.1 KB
    __shared__ __align__(16) float sh_ssqp[TOK_PER_BLK][PCOL];
    __shared__ float sh_M[TOK_PER_BLK][16];

    const int tid  = threadIdx.x;
    const int wave = tid >> 6;
    const int lane = tid & 63;
    const long tok0 = (long)blockIdx.x * TOK_PER_BLK;

    // ---------- Phase 1: nontemporal x -> fp32 sumsq -> packed f16 ----------
    const f32x4* hp = (const f32x4*)resid + tok0 * 1024;
    half2_t xh[TOK_PER_BLK][8];
    #pragma unroll
    for (int m = 0; m < TOK_PER_BLK; ++m) {
        f32x4 pf[4];
        #pragma unroll
        for (int q = 0; q < 4; ++q)
            pf[q] = __builtin_nontemporal_load(&hp[m * 1024 + q * 256 + tid]);
        float s = 0.f;
        #pragma unroll
        for (int q = 0; q < 4; ++q) {
            f32x4 v = pf[q];
            s += v.x * v.x + v.y * v.y + v.z * v.z + v.w * v.w;
            xh[m][2 * q]     = half2_t{(_Float16)v.x, (_Float16)v.y};
            xh[m][2 * q + 1] = half2_t{(_Float16)v.z, (_Float16)v.w};
        }
        s += __shfl_xor(s, 1, 64);            // DPP quad-perm
        s += __shfl_xor(s, 2, 64);            // DPP quad-perm
        if ((lane & 3) == 0) sh_ssqp[m][wave * 16 + (lane >> 2)] = s;
    }

    // ---------- Phase 2: 24 dots via fdot2, depth-4 (quad) prefetch ---------
    const uint4* wp = (const uint4*)(wf + (size_t)(blockIdx.x & (WCOPY - 1)) * WCOPY_U32);

    auto load_row = [&](int e, uint4 (&w)[2]) {
        const uint4* wr = wp + ((size_t)e << 9);
        w[0] = wr[tid];
        w[1] = wr[256 + tid];
    };
#define H2(u) __builtin_bit_cast(half2_t, (u))
    auto comp_row = [&](int e, const uint4 (&W)[2]) {
        #pragma unroll
        for (int m = 0; m < TOK_PER_BLK; ++m) {
            float a0 = 0.f, a1 = 0.f;         // two 4-deep chains
            a0 = __builtin_amdgcn_fdot2(H2(W[0].x), xh[m][0], a0, false);
            a0 = __builtin_amdgcn_fdot2(H2(W[0].y), xh[m][1], a0, false);
            a0 = __builtin_amdgcn_fdot2(H2(W[0].z), xh[m][2], a0, false);
            a0 = __builtin_amdgcn_fdot2(H2(W[0].w), xh[m][3], a0, false);
            a1 = __builtin_amdgcn_fdot2(H2(W[1].x), xh[m][4], a1, false);
            a1 = __builtin_amdgcn_fdot2(H2(W[1].y), xh[m][5], a1, false);
            a1 = __builtin_amdgcn_fdot2(H2(W[1].z), xh[m][6], a1, false);
            a1 = __builtin_amdgcn_fdot2(H2(W[1].w), xh[m][7], a1, false);
            float a = a0 + a1;
            a += __shfl_xor(a, 1, 64);        // DPP
            a += __shfl_xor(a, 2, 64);        // DPP
            if ((lane & 3) == 0)
                sh_part[e * TOK_PER_BLK + m][wave * 16 + (lane >> 2)] = a;
        }
    };
#undef H2

    uint4 wA[2], wB[2], wC[2], wD[2];
    load_row(0, wA);
    load_row(1, wB);
    load_row(2, wC);
    load_row(3, wD);
    #pragma unroll 1
    for (int c = 0; c < 6; ++c) {            // rows 4c .. 4c+3
        comp_row(4 * c + 0, wA);
        if (4 * c + 4 < NROWS) load_row(4 * c + 4, wA);
        comp_row(4 * c + 1, wB);
        if (4 * c + 5 < NROWS) load_row(4 * c + 5, wB);
        comp_row(4 * c + 2, wC);
        if (4 * c + 6 < NROWS) load_row(4 * c + 6, wC);
        comp_row(4 * c + 3, wD);
        if (4 * c + 7 < NROWS) load_row(4 * c + 7, wD);
    }
    __syncthreads();                          // barrier #1: partials visible

    // ------ Phase 3: merged reduce + sinkhorn + gates (wave m -> token m) ---
    if (wave < TOK_PER_BLK) {
        const int m   = wave;
        const int idx = lane & 15;     // (i,j): i = idx>>2, j = idx&3
        const int jj  = idx & 3;

        // staggered lane-local reduction: start col = rot, wrap at 16.
        auto row_sum = [&](const float* base, int rot) {
            const float4* s4p = (const float4*)base;
            float4 s4 = make_float4(0.f, 0.f, 0.f, 0.f);
            #pragma unroll
            for (int j = 0; j < 16; ++j) {
                float4 v = s4p[(rot + j) & 15];
                s4.x += v.x; s4.y += v.y; s4.z += v.z; s4.w += v.w;
            }
            return s4.x + s4.y + s4.z + s4.w;
        };
        float ss       = row_sum(&sh_ssqp[m][0], 0);                     // bcast
        float raw_idx  = row_sum(&sh_part[idx * TOK_PER_BLK + m][0], idx);
        float raw_pre  = row_sum(&sh_part[(16 + jj) * TOK_PER_BLK + m][0], idx);
        float raw_post = row_sum(&sh_part[(20 + jj) * TOK_PER_BLK + m][0], idx);

        float scale = 64.0f / fmaxf(sqrtf(ss), 1e-12f);

        const float a_res  = p_alpha_res[0];
        const float a_pre  = p_alpha_pre[0];
        const float a_post = p_alpha_post[0];

        float Z = (beta_res[idx] + a_res * scale * raw_idx) * TAU_INV;
        float u = 0.f, v = 0.f;
        #pragma unroll 1
        for (int it = 0; it < 10; ++it) {
            float tv = Z + v;
            float mx = tv;
            mx = fmaxf(mx, __shfl_xor(mx, 1, 64));
            mx = fmaxf(mx, __shfl_xor(mx, 2, 64));
            float sm = __expf(tv - mx);
            sm += __shfl_xor(sm, 1, 64);
            sm += __shfl_xor(sm, 2, 64);
            u = -(mx + __logf(sm));
            tv = Z + u;
            mx = tv;
            mx = fmaxf(mx, __shfl_xor(mx, 4, 64));
            mx = fmaxf(mx, __shfl_xor(mx, 8, 64));
            sm = __expf(tv - mx);
            sm += __shfl_xor(sm, 4, 64);
            sm += __shfl_xor(sm, 8, 64);
            v = -(mx + __logf(sm));
        }
        float P = __expf(Z + u + v);           // Hres[i][j]

        float lpre = beta_pre[jj] + a_pre * scale * raw_pre;
        float mxp = lpre;
        mxp = fmaxf(mxp, __shfl_xor(mxp, 1, 64));
        mxp = fmaxf(mxp, __shfl_xor(mxp, 2, 64));
        float ep = __expf(lpre - mxp);
        float sp = ep;
        sp += __shfl_xor(sp, 1, 64);
        sp += __shfl_xor(sp, 2, 64);
        float hpre = ep / sp;                  // Hpre[jj]
        float lpost = beta_post[jj] + a_post * scale * raw_post;
        float hpost = 2.0f / (1.0f + __expf(-lpost));  // Hpost[jj]

        float hpost_i = __shfl(hpost, idx >> 2, 64);
        float Mv = P + hpost_i * hpre;         // M = Hres + Hpost x Hpre
        if (lane < 16) sh_M[m][idx] = Mv;
    }
    __syncthreads();                          // barrier #2: M visible

    // ---------- Phase 4: out = M . x (f16 x), nontemporal stores ------------
    #pragma unroll
    for (int m = 0; m < TOK_PER_BLK; ++m) {
        float Mv[16];
        #pragma unroll
        for (int k = 0; k < 16; ++k) Mv[k] = sh_M[m][k];

        float xm[16];
        #pragma unroll
        for (int q = 0; q < 4; ++q) {
            xm[4*q + 0] = (float)xh[m][2*q][0];
            xm[4*q + 1] = (float)xh[m][2*q][1];
            xm[4*q + 2] = (float)xh[m][2*q + 1][0];
            xm[4*q + 3] = (float)xh[m][2*q + 1][1];
        }

        f32x4* op = (f32x4*)out + (tok0 + m) * 1024;
        #pragma unroll
        for (int i = 0; i < 4; ++i) {
            f32x4 o;
            o.x = Mv[i*4+0]*xm[0] + Mv[i*4+1]*xm[4]  + Mv[i*4+2]*xm[8]  + Mv[i*4+3]*xm[12];
            o.y = Mv[i*4+0]*xm[1] + Mv[i*4+1]*xm[5]  + Mv[i*4+2]*xm[9]  + Mv[i*4+3]*xm[13];
            o.z = Mv[i*4+0]*xm[2] + Mv[i*4+1]*xm[6]  + Mv[i*4+2]*xm[10] + Mv[i*4+3]*xm[14];
            o.w = Mv[i*4+0]*xm[3] + Mv[i*4+1]*xm[7]  + Mv[i*4+2]*xm[11] + Mv[i*4+3]*xm[15];
            __builtin_nontemporal_store(o, &op[i * 256 + tid]);
        }
    }
}

extern "C" void kernel_launch(void* const* d_in, const int* in_sizes, int n_in,
                              void* d_out, int out_size, void* d_ws, size_t ws_size,
                              hipStream_t stream) {
    const float* resid      = (const float*)d_in[0];
    const float* gamma      = (const float*)d_in[1];
    const float* w_res      = (const float*)d_in[2];
    const float* w_pre      = (const float*)d_in[3];
    const float* w_post     = (const float*)d_in[4];
    const float* beta_res   = (const float*)d_in[5];
    const float* beta_pre   = (const float*)d_in[6];
    const float* beta_post  = (const float*)d_in[7];
    const float* alpha_res  = (const float*)d_in[8];
    const float* alpha_pre  = (const float*)d_in[9];
    const float* alpha_post = (const float*)d_in[10];
    float* out = (float*)d_out;

    unsigned int* wf = (unsigned int*)d_ws;       // 8 copies x 192 KB = 1.5 MB
    (void)ws_size;

    fold_gamma<<<NROWS * 2048 / THREADS, THREADS, 0, stream>>>(
        w_res, w_pre, w_post, gamma, wf);

    const int ntok = in_sizes[0] / 4096;          // B*T = 8192
    const int grid = ntok / TOK_PER_BLK;          // 4096

    hc_fused<<<grid, THREADS, 0, stream>>>(resid, wf, beta_res, beta_pre,
                                           beta_post, alpha_res, alpha_pre,
                                           alpha_post, out);
}

// Round 16
// 280.659 us; speedup vs baseline: 1.1710x; 1.1710x over previous
//
#include <hip/hip_runtime.h>
#include <math.h>

#define TOK_PER_BLK 2
#define THREADS 256
#define NROWS 24
#define PCOL 68        // 64 partials + 4 pad
#define TAU_INV 20.0f  // 1/0.05
#define WCOPY 8        // weight replicas (per-XCD L2 affinity via blockIdx&7)
#define WROW_U32 2048  // uint32 per row
#define WCOPY_U32 (NROWS * WROW_U32)

typedef _Float16 half2_t __attribute__((ext_vector_type(2)));
typedef float    f32x4  __attribute__((ext_vector_type(4)));

// ---------------------------------------------------------------------------
// Prelude: fold (1+gamma) into the 24 weight rows, f16 pairs, PERMUTED so in
// hc_fused thread tid's two uint4 loads deliver the 16 k-elements matching
// its x quads (k = q*1024 + 4*tid .. +3, q=0..3). 8 identical copies;
// consecutive blocks (round-robin across XCDs) pick copy blockIdx&7.
// ---------------------------------------------------------------------------
__global__ void fold_gamma(const float* __restrict__ w_res,
                           const float* __restrict__ w_pre,
                           const float* __restrict__ w_post,
                           const float* __restrict__ gamma,
                           unsigned int* __restrict__ wf) {
    const int idx = blockIdx.x * THREADS + threadIdx.x;   // 0 .. 24*2048-1
    const int row = idx >> 11;
    const int j   = idx & 2047;
    const int o   = j >> 2;
    const int pp  = j & 3;
    const int t   = o & 255;
    const int quad = pp >> 1;
    int base;
    if (o < 256) base = (quad == 0) ? (4 * t)        : (1024 + 4 * t);
    else         base = (quad == 0) ? (2048 + 4 * t) : (3072 + 4 * t);
    const int k0 = base + 2 * (pp & 1);

    const float* src = (row < 16) ? (w_res + ((size_t)row << 12))
                     : (row < 20) ? (w_pre + ((size_t)(row - 16) << 12))
                                  : (w_post + ((size_t)(row - 20) << 12));
    float v0 = src[k0]     * (1.0f + gamma[k0]);
    float v1 = src[k0 + 1] * (1.0f + gamma[k0 + 1]);
    union { _Float16 h[2]; unsigned int u; } cvt;
    cvt.h[0] = (_Float16)v0;
    cvt.h[1] = (_Float16)v1;
    #pragma unroll
    for (int c = 0; c < WCOPY; ++c)
        wf[(size_t)c * WCOPY_U32 + idx] = cvt.u;
}

// ---------------------------------------------------------------------------
// R20 = exact revert to R17, the session's best verified kernel (91.5 us,
// VGPR 52, occ 40%, zero spill, bench 281).
// FINAL LEDGER: R4 140 -> R8 128 (spill killed via (256,2)) -> R9 121 (bf16
// w) -> R11 115 (fdot2) -> R15 91 (nt streams + 8x replicas + depth-4
// prefetch: weight L2-residency was the one big lever). Falsified levers:
// occupancy up (R10), weight bytes down (R9/R16), chain depth (R17-null-but-
// kept), barrier thinning (R18/R19: merged reduce costs ~40 VGPR -> occ 22%,
// twice), fat blocks (R13/R16), kernel split (R12). Residual ~50 us over the
// 41 us HBM floor = correlated wave stalls intrinsic to this fused shape.
// ALLOCATOR LAW (R4/5/7/8/13): keep (256,2); load bursts <= 8 per window.
// Tripwire: WRITE_SIZE != 131072 KB = spill returned.
// ---------------------------------------------------------------------------
__global__ __launch_bounds__(THREADS, 2)
void hc_fused(const float* __restrict__ resid,
              const unsigned int* __restrict__ wf,
              const float* __restrict__ beta_res,
              const float* __restrict__ beta_pre,
              const float* __restrict__ beta_post,
              const float* __restrict__ p_alpha_res,
              const float* __restrict__ p_alpha_pre,
              const float* __restrict__ p_alpha_post,
              float* __restrict__ out)
{
    __shared__ __align__(16) float sh_part[NROWS * TOK_PER_BLK][PCOL]; // 13.1 KB
    __shared__ __align__(16) float sh_ssqp[TOK_PER_BLK][PCOL];
    __shared__ float sh_raw[TOK_PER_BLK][NROWS];
    __shared__ float sh_ssq[TOK_PER_BLK];
    __shared__ float sh_M[TOK_PER_BLK][16];

    const int tid  = threadIdx.x;
    const int wave = tid >> 6;
    const int lane = tid & 63;
    const long tok0 = (long)blockIdx.x * TOK_PER_BLK;

    // ---------- Phase 1: nontemporal x -> fp32 sumsq -> packed f16 ----------
    const f32x4* hp = (const f32x4*)resid + tok0 * 1024;
    half2_t xh[TOK_PER_BLK][8];
    #pragma unroll
    for (int m = 0; m < TOK_PER_BLK; ++m) {
        f32x4 pf[4];
        #pragma unroll
        for (int q = 0; q < 4; ++q)
            pf[q] = __builtin_nontemporal_load(&hp[m * 1024 + q * 256 + tid]);
        float s = 0.f;
        #pragma unroll
        for (int q = 0; q < 4; ++q) {
            f32x4 v = pf[q];
            s += v.x * v.x + v.y * v.y + v.z * v.z + v.w * v.w;
            xh[m][2 * q]     = half2_t{(_Float16)v.x, (_Float16)v.y};
            xh[m][2 * q + 1] = half2_t{(_Float16)v.z, (_Float16)v.w};
        }
        s += __shfl_xor(s, 1, 64);            // DPP quad-perm
        s += __shfl_xor(s, 2, 64);            // DPP quad-perm
        if ((lane & 3) == 0) sh_ssqp[m][wave * 16 + (lane >> 2)] = s;
    }

    // ---------- Phase 2: 24 dots via fdot2, depth-4 (quad) prefetch ---------
    const uint4* wp = (const uint4*)(wf + (size_t)(blockIdx.x & (WCOPY - 1)) * WCOPY_U32);

    auto load_row = [&](int e, uint4 (&w)[2]) {
        const uint4* wr = wp + ((size_t)e << 9);
        w[0] = wr[tid];
        w[1] = wr[256 + tid];
    };
#define H2(u) __builtin_bit_cast(half2_t, (u))
    auto comp_row = [&](int e, const uint4 (&W)[2]) {
        #pragma unroll
        for (int m = 0; m < TOK_PER_BLK; ++m) {
            float a0 = 0.f, a1 = 0.f;         // two 4-deep chains (was 8-deep)
            a0 = __builtin_amdgcn_fdot2(H2(W[0].x), xh[m][0], a0, false);
            a0 = __builtin_amdgcn_fdot2(H2(W[0].y), xh[m][1], a0, false);
            a0 = __builtin_amdgcn_fdot2(H2(W[0].z), xh[m][2], a0, false);
            a0 = __builtin_amdgcn_fdot2(H2(W[0].w), xh[m][3], a0, false);
            a1 = __builtin_amdgcn_fdot2(H2(W[1].x), xh[m][4], a1, false);
            a1 = __builtin_amdgcn_fdot2(H2(W[1].y), xh[m][5], a1, false);
            a1 = __builtin_amdgcn_fdot2(H2(W[1].z), xh[m][6], a1, false);
            a1 = __builtin_amdgcn_fdot2(H2(W[1].w), xh[m][7], a1, false);
            float a = a0 + a1;
            a += __shfl_xor(a, 1, 64);        // DPP, ~2cy
            a += __shfl_xor(a, 2, 64);        // DPP, ~2cy
            if ((lane & 3) == 0)
                sh_part[e * TOK_PER_BLK + m][wave * 16 + (lane >> 2)] = a;
        }
    };
#undef H2

    uint4 wA[2], wB[2], wC[2], wD[2];
    load_row(0, wA);
    load_row(1, wB);
    load_row(2, wC);
    load_row(3, wD);
    #pragma unroll 1
    for (int c = 0; c < 6; ++c) {            // rows 4c .. 4c+3
        comp_row(4 * c + 0, wA);
        if (4 * c + 4 < NROWS) load_row(4 * c + 4, wA);
        comp_row(4 * c + 1, wB);
        if (4 * c + 5 < NROWS) load_row(4 * c + 5, wB);
        comp_row(4 * c + 2, wC);
        if (4 * c + 6 < NROWS) load_row(4 * c + 6, wC);
        comp_row(4 * c + 3, wD);
        if (4 * c + 7 < NROWS) load_row(4 * c + 7, wD);
    }
    __syncthreads();

    // ---------------- Reduce: 64 partials per (row,token) ----------------
    if (tid < NROWS * TOK_PER_BLK) {           // 48 threads: one (row,token)
        const float4* src = (const float4*)&sh_part[tid][0];
        float4 s4 = src[0];
        #pragma unroll
        for (int j = 1; j < 16; ++j) {
            float4 v = src[j];
            s4.x += v.x; s4.y += v.y; s4.z += v.z; s4.w += v.w;
        }
        sh_raw[tid & (TOK_PER_BLK - 1)][tid >> 1] = s4.x + s4.y + s4.z + s4.w;
    } else if (tid < NROWS * TOK_PER_BLK + TOK_PER_BLK) {
        const int m = tid - NROWS * TOK_PER_BLK;
        const float4* src = (const float4*)&sh_ssqp[m][0];
        float4 s4 = src[0];
        #pragma unroll
        for (int j = 1; j < 16; ++j) {
            float4 v = src[j];
            s4.x += v.x; s4.y += v.y; s4.z += v.z; s4.w += v.w;
        }
        sh_ssq[m] = s4.x + s4.y + s4.z + s4.w;
    }
    __syncthreads();

    // ---------------- Phase 3: sinkhorn + gates (wave m -> token m) ---------
    if (wave < TOK_PER_BLK) {
        const int m   = wave;
        const int idx = lane & 15;     // (i,j): i = idx>>2, j = idx&3
        const int jj  = idx & 3;

        float ss    = sh_ssq[m];
        float scale = 64.0f / fmaxf(sqrtf(ss), 1e-12f);

        const float a_res  = p_alpha_res[0];
        const float a_pre  = p_alpha_pre[0];
        const float a_post = p_alpha_post[0];

        float Z = (beta_res[idx] + a_res * scale * sh_raw[m][idx]) * TAU_INV;
        float u = 0.f, v = 0.f;
        #pragma unroll 1
        for (int it = 0; it < 10; ++it) {
            float tv = Z + v;
            float mx = tv;
            mx = fmaxf(mx, __shfl_xor(mx, 1, 64));
            mx = fmaxf(mx, __shfl_xor(mx, 2, 64));
            float sm = __expf(tv - mx);
            sm += __shfl_xor(sm, 1, 64);
            sm += __shfl_xor(sm, 2, 64);
            u = -(mx + __logf(sm));
            tv = Z + u;
            mx = tv;
            mx = fmaxf(mx, __shfl_xor(mx, 4, 64));
            mx = fmaxf(mx, __shfl_xor(mx, 8, 64));
            sm = __expf(tv - mx);
            sm += __shfl_xor(sm, 4, 64);
            sm += __shfl_xor(sm, 8, 64);
            v = -(mx + __logf(sm));
        }
        float P = __expf(Z + u + v);           // Hres[i][j]

        float lpre = beta_pre[jj] + a_pre * scale * sh_raw[m][16 + jj];
        float mxp = lpre;
        mxp = fmaxf(mxp, __shfl_xor(mxp, 1, 64));
        mxp = fmaxf(mxp, __shfl_xor(mxp, 2, 64));
        float ep = __expf(lpre - mxp);
        float sp = ep;
        sp += __shfl_xor(sp, 1, 64);
        sp += __shfl_xor(sp, 2, 64);
        float hpre = ep / sp;                  // Hpre[jj]
        float lpost = beta_post[jj] + a_post * scale * sh_raw[m][20 + jj];
        float hpost = 2.0f / (1.0f + __expf(-lpost));  // Hpost[jj]

        float hpost_i = __shfl(hpost, idx >> 2, 64);
        float Mv = P + hpost_i * hpre;         // M = Hres + Hpost x Hpre
        if (lane < 16) sh_M[m][idx] = Mv;
    }
    __syncthreads();

    // ---------- Phase 4: out = M . x (f16 x), nontemporal stores ------------
    #pragma unroll
    for (int m = 0; m < TOK_PER_BLK; ++m) {
        float Mv[16];
        #pragma unroll
        for (int k = 0; k < 16; ++k) Mv[k] = sh_M[m][k];

        float xm[16];
        #pragma unroll
        for (int q = 0; q < 4; ++q) {
            xm[4*q + 0] = (float)xh[m][2*q][0];
            xm[4*q + 1] = (float)xh[m][2*q][1];
            xm[4*q + 2] = (float)xh[m][2*q + 1][0];
            xm[4*q + 3] = (float)xh[m][2*q + 1][1];
        }

        f32x4* op = (f32x4*)out + (tok0 + m) * 1024;
        #pragma unroll
        for (int i = 0; i < 4; ++i) {
            f32x4 o;
            o.x = Mv[i*4+0]*xm[0] + Mv[i*4+1]*xm[4]  + Mv[i*4+2]*xm[8]  + Mv[i*4+3]*xm[12];
            o.y = Mv[i*4+0]*xm[1] + Mv[i*4+1]*xm[5]  + Mv[i*4+2]*xm[9]  + Mv[i*4+3]*xm[13];
            o.z = Mv[i*4+0]*xm[2] + Mv[i*4+1]*xm[6]  + Mv[i*4+2]*xm[10] + Mv[i*4+3]*xm[14];
            o.w = Mv[i*4+0]*xm[3] + Mv[i*4+1]*xm[7]  + Mv[i*4+2]*xm[11] + Mv[i*4+3]*xm[15];
            __builtin_nontemporal_store(o, &op[i * 256 + tid]);
        }
    }
}

extern "C" void kernel_launch(void* const* d_in, const int* in_sizes, int n_in,
                              void* d_out, int out_size, void* d_ws, size_t ws_size,
                              hipStream_t stream) {
    const float* resid      = (const float*)d_in[0];
    const float* gamma      = (const float*)d_in[1];
    const float* w_res      = (const float*)d_in[2];
    const float* w_pre      = (const float*)d_in[3];
    const float* w_post     = (const float*)d_in[4];
    const float* beta_res   = (const float*)d_in[5];
    const float* beta_pre   = (const float*)d_in[6];
    const float* beta_post  = (const float*)d_in[7];
    const float* alpha_res  = (const float*)d_in[8];
    const float* alpha_pre  = (const float*)d_in[9];
    const float* alpha_post = (const float*)d_in[10];
    float* out = (float*)d_out;

    unsigned int* wf = (unsigned int*)d_ws;       // 8 copies x 192 KB = 1.5 MB
    (void)ws_size;

    fold_gamma<<<NROWS * 2048 / THREADS, THREADS, 0, stream>>>(
        w_res, w_pre, w_post, gamma, wf);

    const int ntok = in_sizes[0] / 4096;          // B*T = 8192
    const int grid = ntok / TOK_PER_BLK;          // 4096

    hc_fused<<<grid, THREADS, 0, stream>>>(resid, wf, beta_res, beta_pre,
                                           beta_post, alpha_res, alpha_pre,
                                           alpha_post, out);
}